// Round 10
// baseline (214.220 us; speedup 1.0000x reference)
//
#include <hip/hip_runtime.h>

#define NSTEPS 64

typedef __attribute__((ext_vector_type(4)))  float  float4_;   // 16x16 MFMA C/D
typedef __attribute__((ext_vector_type(2)))  __fp16 half2_;    // packed f16
typedef __attribute__((ext_vector_type(8)))  __fp16 half8_;    // f16 MFMA A/B operand

__device__ __forceinline__ half2_ relu_pk_f16(float a, float b) {
    half2_ h = __builtin_amdgcn_cvt_pkrtz(a, b);               // v_cvt_pkrtz_f16_f32
    return __builtin_elementwise_max(h, (half2_)(__fp16)0);    // v_pk_max_f16
}

// R24 (this round): R9's z-space 16x16 structure + TWO independent chains
// per wave (32 samples/wave, 4096 waves). Evidence: VALU-busy/instr ~= 7.7
// cyc vs 2-cyc issue floor -> ~70% exposed dependency latency; R3 showed
// 2-chain ILP doubles per-wave throughput when residency holds. 16-shape
// fragments (4-reg C/D) keep 2-chain total regs ~120 -> 3-4 waves/SIMD
// -> 6-8 streams. setprio REMOVED: its side-effecting toggles fence the
// scheduler and would block cross-chain interleave in an in-order wave.
// Numerics identical to R9 (validated): zb recurrence, Mh(dt2)/Mz(dt6),
// Qd=2Q for st3, C-operand carries zb+ci*cH, C3=6*b3, y+=dt6*D3.
__global__ __launch_bounds__(64, 3)
void ode_rk4_mfma(const float* __restrict__ x,
                  const float* __restrict__ samples,
                  const float* __restrict__ w1, const float* __restrict__ b1,
                  const float* __restrict__ w2, const float* __restrict__ b2,
                  const float* __restrict__ w3, const float* __restrict__ b3,
                  const float* __restrict__ w_out, const float* __restrict__ b_out,
                  float* __restrict__ out, int B)
{
    const int lane  = threadIdx.x & 63;
    const int col16 = lane & 15;              // this lane's sample (mod 16)
    const int quad  = lane >> 4;              // 0..3 (k-group / row-group)

    const int rowA = blockIdx.x * 32 + col16; // chain A sample
    const int rowB = rowA + 16;               // chain B sample

    auto sig = [](int p) -> int {
        int q = (p & 15) >> 2, r = p & 3;
        return q * 8 + r + ((p < 16) ? 0 : 4);
    };

    // ---- scalars ----
    const float maxT = samples[7];
    const float dt   = maxT / 64.0f;
    const float dt2  = 0.5f * dt;
    const float dt6  = dt / 6.0f;

    union F { half2_ h2[4]; half8_ h8; };

    // ---- persistent MFMA operands (SHARED by both chains) ----
    F Mh[2], Mz[2];
#pragma unroll
    for (int H = 0; H < 2; ++H) {
        int u = sig(16 * H + col16);
#pragma unroll
        for (int pp = 0; pp < 4; ++pp) {
            int kk = quad * 8 + 2 * pp;
            float m0 = w3[kk * 3 + 0] * w1[0 * 32 + u]
                     + w3[kk * 3 + 1] * w1[1 * 32 + u]
                     + w3[kk * 3 + 2] * w1[2 * 32 + u];
            float m1 = w3[(kk + 1) * 3 + 0] * w1[0 * 32 + u]
                     + w3[(kk + 1) * 3 + 1] * w1[1 * 32 + u]
                     + w3[(kk + 1) * 3 + 2] * w1[2 * 32 + u];
            Mh[H].h2[pp] = (half2_){(__fp16)(dt2 * m0), (__fp16)(dt2 * m1)};
            Mz[H].h2[pp] = (half2_){(__fp16)(dt6 * m0), (__fp16)(dt6 * m1)};
        }
    }

    F A2[2];
    float4_ Cb[2];
#pragma unroll
    for (int H = 0; H < 2; ++H) {
        int u = sig(16 * H + col16);
#pragma unroll
        for (int pp = 0; pp < 4; ++pp) {
            int kk = quad * 8 + 2 * pp;
            A2[H].h2[pp] = (half2_){(__fp16)w2[kk * 32 + u], (__fp16)w2[(kk + 1) * 32 + u]};
        }
#pragma unroll
        for (int r = 0; r < 4; ++r)
            Cb[H][r] = b2[sig(16 * H + quad * 4 + r)];
    }

    F A3;
    {
        const int  d    = col16 & 3;
        const bool live = d < 3;
#pragma unroll
        for (int pp = 0; pp < 4; ++pp) {
            int kk = quad * 8 + 2 * pp;
            A3.h2[pp] = live
                ? (half2_){(__fp16)w3[kk * 3 + d], (__fp16)w3[(kk + 1) * 3 + d]}
                : (half2_)(__fp16)0.0f;
        }
    }
    float4_ C3;
#pragma unroll
    for (int r = 0; r < 4; ++r)
        C3[r] = (r < 3) ? 6.0f * b3[r] : 0.0f;

    float4_ cH[2];
#pragma unroll
    for (int H = 0; H < 2; ++H)
#pragma unroll
        for (int r = 0; r < 4; ++r) {
            int u = sig(16 * H + quad * 4 + r);
            cH[H][r] = dt2 * (b3[0] * w1[0 * 32 + u] + b3[1] * w1[1 * 32 + u] + b3[2] * w1[2 * 32 + u]);
        }

    int sidx[8];
    unsigned long long smask = 0ull;
#pragma unroll
    for (int j = 0; j < 8; ++j) {
        int id = (int)rintf(samples[j] / dt) - 1;   // jnp.round = RNE
        id = id < 0 ? 0 : (id > NSTEPS - 1 ? NSTEPS - 1 : id);
        id = __builtin_amdgcn_readfirstlane(id);    // wave-uniform -> SGPR
        sidx[j] = id;
        smask |= 1ull << id;
    }
    const float wo0 = w_out[0], wo1 = w_out[1], wo2 = w_out[2];
    const float bo  = b_out[0];

    float yA0 = x[(size_t)rowA * 3 + 0];
    float yA1 = x[(size_t)rowA * 3 + 1];
    float yA2 = x[(size_t)rowA * 3 + 2];
    float yB0 = x[(size_t)rowB * 3 + 0];
    float yB1 = x[(size_t)rowB * 3 + 1];
    float yB2 = x[(size_t)rowB * 3 + 2];

    // ---- prologue: zb = y*W1 + b1 in D-layout, both chains ----
    float4_ zbA0, zbA1, zbB0, zbB1;
    {
        F A1y[2];
#pragma unroll
        for (int H = 0; H < 2; ++H) {
            if (quad == 0) {
                int u = sig(16 * H + col16);
                A1y[H].h2[0] = (half2_){(__fp16)w1[0 * 32 + u], (__fp16)w1[1 * 32 + u]};
                A1y[H].h2[1] = (half2_){(__fp16)w1[2 * 32 + u], (__fp16)b1[u]};
                A1y[H].h2[2] = (half2_)(__fp16)0.0f;
                A1y[H].h2[3] = (half2_)(__fp16)0.0f;
            } else {
#pragma unroll
                for (int pp = 0; pp < 4; ++pp) A1y[H].h2[pp] = (half2_)(__fp16)0.0f;
            }
        }
        float4_ Zc;
#pragma unroll
        for (int r = 0; r < 4; ++r) Zc[r] = 0.0f;
        half2_ aA = __builtin_amdgcn_cvt_pkrtz(yA0, yA1);
        half2_ bA = __builtin_amdgcn_cvt_pkrtz(yA2, 1.0f);
        half2_ aB = __builtin_amdgcn_cvt_pkrtz(yB0, yB1);
        half2_ bB = __builtin_amdgcn_cvt_pkrtz(yB2, 1.0f);
        F ByA, ByB;
        ByA.h2[0] = aA; ByA.h2[1] = bA; ByA.h2[2] = aA; ByA.h2[3] = bA;
        ByB.h2[0] = aB; ByB.h2[1] = bB; ByB.h2[2] = aB; ByB.h2[3] = bB;
        zbA0 = __builtin_amdgcn_mfma_f32_16x16x32_f16(A1y[0].h8, ByA.h8, Zc, 0, 0, 0);
        zbA1 = __builtin_amdgcn_mfma_f32_16x16x32_f16(A1y[1].h8, ByA.h8, Zc, 0, 0, 0);
        zbB0 = __builtin_amdgcn_mfma_f32_16x16x32_f16(A1y[0].h8, ByB.h8, Zc, 0, 0, 0);
        zbB1 = __builtin_amdgcn_mfma_f32_16x16x32_f16(A1y[1].h8, ByB.h8, Zc, 0, 0, 0);
    }

    const half2_ two = (half2_)(__fp16)2.0f;

    // one full RK4 step for one chain (inlined twice; NO setprio/fences so
    // the scheduler can interleave the two chains' instructions)
    auto rk_step = [&](float4_& zb0, float4_& zb1, float& y0, float& y1, float& y2) {
        F P, Q, S;
        // st0: P directly from zb
        P.h2[0] = relu_pk_f16(zb0[0], zb0[1]);
        P.h2[1] = relu_pk_f16(zb0[2], zb0[3]);
        P.h2[2] = relu_pk_f16(zb1[0], zb1[1]);
        P.h2[3] = relu_pk_f16(zb1[2], zb1[3]);
        float4_ D2_0 = __builtin_amdgcn_mfma_f32_16x16x32_f16(A2[0].h8, P.h8, Cb[0], 0, 0, 0);
        float4_ D2_1 = __builtin_amdgcn_mfma_f32_16x16x32_f16(A2[1].h8, P.h8, Cb[1], 0, 0, 0);
        Q.h2[0] = relu_pk_f16(D2_0[0], D2_0[1]);
        Q.h2[1] = relu_pk_f16(D2_0[2], D2_0[3]);
        Q.h2[2] = relu_pk_f16(D2_1[0], D2_1[1]);
        Q.h2[3] = relu_pk_f16(D2_1[2], D2_1[3]);
#pragma unroll
        for (int pp = 0; pp < 4; ++pp) S.h2[pp] = Q.h2[pp];      // ca=1

        float4_ zh0 = zb0 + cH[0];
        float4_ zh1 = zb1 + cH[1];

        // st1, st2 (ca=2)
#pragma unroll
        for (int st = 1; st <= 2; ++st) {
            float4_ D1_0 = __builtin_amdgcn_mfma_f32_16x16x32_f16(Mh[0].h8, Q.h8, zh0, 0, 0, 0);
            float4_ D1_1 = __builtin_amdgcn_mfma_f32_16x16x32_f16(Mh[1].h8, Q.h8, zh1, 0, 0, 0);
            P.h2[0] = relu_pk_f16(D1_0[0], D1_0[1]);
            P.h2[1] = relu_pk_f16(D1_0[2], D1_0[3]);
            P.h2[2] = relu_pk_f16(D1_1[0], D1_1[1]);
            P.h2[3] = relu_pk_f16(D1_1[2], D1_1[3]);
            float4_ E0 = __builtin_amdgcn_mfma_f32_16x16x32_f16(A2[0].h8, P.h8, Cb[0], 0, 0, 0);
            float4_ E1 = __builtin_amdgcn_mfma_f32_16x16x32_f16(A2[1].h8, P.h8, Cb[1], 0, 0, 0);
            Q.h2[0] = relu_pk_f16(E0[0], E0[1]);
            Q.h2[1] = relu_pk_f16(E0[2], E0[3]);
            Q.h2[2] = relu_pk_f16(E1[0], E1[1]);
            Q.h2[3] = relu_pk_f16(E1[2], E1[3]);
#pragma unroll
            for (int pp = 0; pp < 4; ++pp)
                S.h2[pp] += two * Q.h2[pp];                      // v_pk_fma_f16
        }

        // st3 (ca=1): C = zb + 2*cH; feed 2*Q into dt2-scaled M
        zh0 = zh0 + cH[0];
        zh1 = zh1 + cH[1];
        F Qd;
#pragma unroll
        for (int pp = 0; pp < 4; ++pp) Qd.h2[pp] = Q.h2[pp] + Q.h2[pp];  // exact x2
        float4_ D1_0 = __builtin_amdgcn_mfma_f32_16x16x32_f16(Mh[0].h8, Qd.h8, zh0, 0, 0, 0);
        float4_ D1_1 = __builtin_amdgcn_mfma_f32_16x16x32_f16(Mh[1].h8, Qd.h8, zh1, 0, 0, 0);
        P.h2[0] = relu_pk_f16(D1_0[0], D1_0[1]);
        P.h2[1] = relu_pk_f16(D1_0[2], D1_0[3]);
        P.h2[2] = relu_pk_f16(D1_1[0], D1_1[1]);
        P.h2[3] = relu_pk_f16(D1_1[2], D1_1[3]);
        float4_ E0 = __builtin_amdgcn_mfma_f32_16x16x32_f16(A2[0].h8, P.h8, Cb[0], 0, 0, 0);
        float4_ E1 = __builtin_amdgcn_mfma_f32_16x16x32_f16(A2[1].h8, P.h8, Cb[1], 0, 0, 0);
        Q.h2[0] = relu_pk_f16(E0[0], E0[1]);
        Q.h2[1] = relu_pk_f16(E0[2], E0[3]);
        Q.h2[2] = relu_pk_f16(E1[0], E1[1]);
        Q.h2[3] = relu_pk_f16(E1[2], E1[3]);
#pragma unroll
        for (int pp = 0; pp < 4; ++pp) S.h2[pp] += Q.h2[pp];     // ca=1

        // y-update + z-update
        float4_ D3 = __builtin_amdgcn_mfma_f32_16x16x32_f16(A3.h8, S.h8, C3, 0, 0, 0);
        zb0 = __builtin_amdgcn_mfma_f32_16x16x32_f16(Mz[0].h8, S.h8, zb0, 0, 0, 0);
        zb1 = __builtin_amdgcn_mfma_f32_16x16x32_f16(Mz[1].h8, S.h8, zb1, 0, 0, 0);
#pragma unroll
        for (int r = 0; r < 4; ++r) {
            zb0[r] = fmaf(2.0f, cH[0][r], zb0[r]);
            zb1[r] = fmaf(2.0f, cH[1][r], zb1[r]);
        }
        y0 = fmaf(dt6, D3[0], y0);
        y1 = fmaf(dt6, D3[1], y1);
        y2 = fmaf(dt6, D3[2], y2);
    };

#pragma unroll 1
    for (int s = 0; s < NSTEPS; ++s) {
        rk_step(zbA0, zbA1, yA0, yA1, yA2);
        rk_step(zbB0, zbB1, yB0, yB1, yB2);

        // wave-uniform SALU fast path: most steps store nothing
        if ((smask >> s) & 1ull) {
            if (quad == 0) {
#pragma unroll
                for (int j = 0; j < 8; ++j) {
                    if (sidx[j] == s) {
                        out[(size_t)j * B + rowA] = fmaf(yA2, wo2, fmaf(yA1, wo1, fmaf(yA0, wo0, bo)));
                        out[(size_t)j * B + rowB] = fmaf(yB2, wo2, fmaf(yB1, wo1, fmaf(yB0, wo0, bo)));
                    }
                }
            }
        }
    }
}

extern "C" void kernel_launch(void* const* d_in, const int* in_sizes, int n_in,
                              void* d_out, int out_size, void* d_ws, size_t ws_size,
                              hipStream_t stream) {
    const float* x       = (const float*)d_in[0];
    const float* samples = (const float*)d_in[1];
    const float* w1      = (const float*)d_in[2];
    const float* b1      = (const float*)d_in[3];
    const float* w2      = (const float*)d_in[4];
    const float* b2      = (const float*)d_in[5];
    const float* w3      = (const float*)d_in[6];
    const float* b3      = (const float*)d_in[7];
    const float* w_out   = (const float*)d_in[8];
    const float* b_out   = (const float*)d_in[9];
    float* out = (float*)d_out;

    const int B = in_sizes[0] / 3;           // 131072
    const int rowsPerBlock = 32;             // 1 wave x 2 chains x 16 samples
    const int grid = (B + rowsPerBlock - 1) / rowsPerBlock;   // 4096
    ode_rk4_mfma<<<grid, 64, 0, stream>>>(
        x, samples, w1, b1, w2, b2, w3, b3, w_out, b_out, out, B);
}

// Round 11
// 208.414 us; speedup vs baseline: 1.0279x; 1.0279x over previous
//
#include <hip/hip_runtime.h>

#define NSTEPS 64

typedef __attribute__((ext_vector_type(4)))  float  float4_;   // 16x16 MFMA C/D
typedef __attribute__((ext_vector_type(2)))  __fp16 half2_;    // packed f16
typedef __attribute__((ext_vector_type(8)))  __fp16 half8_;    // f16 MFMA A/B operand

__device__ __forceinline__ half2_ relu_pk_f16(float a, float b) {
    half2_ h = __builtin_amdgcn_cvt_pkrtz(a, b);               // v_cvt_pkrtz_f16_f32
    return __builtin_elementwise_max(h, (half2_)(__fp16)0);    // v_pk_max_f16
}

// R25 (this round): R9 z-space structure, TWO chains, HAND-INTERLEAVED.
// R10's tell: VGPR=60 (+8 vs R9) => compiler ran rk_step(A) then rk_step(B)
// sequentially, reusing registers — the stream-overlap thesis was never
// tested. Per-SIMD arithmetic from R9/R10 counters: VALU pipe ~20% busy,
// MFMA pipe ~40%, => ~40% of SIMD issue cycles are dependent-chain stalls.
// R3 proved manual statement-interleave doubles per-wave throughput; it
// only lost TLP because 32x32 frags cost too many regs. 16x16 z-space is
// 52 regs/chain -> interleaved dual fits ~125 regs -> 3-4 resident waves
// x 2 chains = 6-8 streams/SIMD. Every A-statement is immediately followed
// by its B-twin with separate named registers.
// Numerics per chain identical to R9/R10 (validated): zb recurrence,
// Mh(dt2)/Mz(dt6), Qd=2Q for st3, C-operand carries zb+ci*cH, C3=6*b3.
__global__ __launch_bounds__(64, 3)
void ode_rk4_mfma(const float* __restrict__ x,
                  const float* __restrict__ samples,
                  const float* __restrict__ w1, const float* __restrict__ b1,
                  const float* __restrict__ w2, const float* __restrict__ b2,
                  const float* __restrict__ w3, const float* __restrict__ b3,
                  const float* __restrict__ w_out, const float* __restrict__ b_out,
                  float* __restrict__ out, int B)
{
    const int lane  = threadIdx.x & 63;
    const int col16 = lane & 15;              // this lane's sample (mod 16)
    const int quad  = lane >> 4;              // 0..3 (k-group / row-group)

    const int rowA = blockIdx.x * 32 + col16; // chain A sample
    const int rowB = rowA + 16;               // chain B sample

    auto sig = [](int p) -> int {
        int q = (p & 15) >> 2, r = p & 3;
        return q * 8 + r + ((p < 16) ? 0 : 4);
    };

    // ---- scalars ----
    const float maxT = samples[7];
    const float dt   = maxT / 64.0f;
    const float dt2  = 0.5f * dt;
    const float dt6  = dt / 6.0f;

    union F { half2_ h2[4]; half8_ h8; };

    // ---- persistent MFMA operands (SHARED by both chains) ----
    F Mh[2], Mz[2];
#pragma unroll
    for (int H = 0; H < 2; ++H) {
        int u = sig(16 * H + col16);
#pragma unroll
        for (int pp = 0; pp < 4; ++pp) {
            int kk = quad * 8 + 2 * pp;
            float m0 = w3[kk * 3 + 0] * w1[0 * 32 + u]
                     + w3[kk * 3 + 1] * w1[1 * 32 + u]
                     + w3[kk * 3 + 2] * w1[2 * 32 + u];
            float m1 = w3[(kk + 1) * 3 + 0] * w1[0 * 32 + u]
                     + w3[(kk + 1) * 3 + 1] * w1[1 * 32 + u]
                     + w3[(kk + 1) * 3 + 2] * w1[2 * 32 + u];
            Mh[H].h2[pp] = (half2_){(__fp16)(dt2 * m0), (__fp16)(dt2 * m1)};
            Mz[H].h2[pp] = (half2_){(__fp16)(dt6 * m0), (__fp16)(dt6 * m1)};
        }
    }

    F A2[2];
    float4_ Cb[2];
#pragma unroll
    for (int H = 0; H < 2; ++H) {
        int u = sig(16 * H + col16);
#pragma unroll
        for (int pp = 0; pp < 4; ++pp) {
            int kk = quad * 8 + 2 * pp;
            A2[H].h2[pp] = (half2_){(__fp16)w2[kk * 32 + u], (__fp16)w2[(kk + 1) * 32 + u]};
        }
#pragma unroll
        for (int r = 0; r < 4; ++r)
            Cb[H][r] = b2[sig(16 * H + quad * 4 + r)];
    }

    F A3;
    {
        const int  d    = col16 & 3;
        const bool live = d < 3;
#pragma unroll
        for (int pp = 0; pp < 4; ++pp) {
            int kk = quad * 8 + 2 * pp;
            A3.h2[pp] = live
                ? (half2_){(__fp16)w3[kk * 3 + d], (__fp16)w3[(kk + 1) * 3 + d]}
                : (half2_)(__fp16)0.0f;
        }
    }
    float4_ C3;
#pragma unroll
    for (int r = 0; r < 4; ++r)
        C3[r] = (r < 3) ? 6.0f * b3[r] : 0.0f;

    float4_ cH[2];
#pragma unroll
    for (int H = 0; H < 2; ++H)
#pragma unroll
        for (int r = 0; r < 4; ++r) {
            int u = sig(16 * H + quad * 4 + r);
            cH[H][r] = dt2 * (b3[0] * w1[0 * 32 + u] + b3[1] * w1[1 * 32 + u] + b3[2] * w1[2 * 32 + u]);
        }

    int sidx[8];
    unsigned long long smask = 0ull;
#pragma unroll
    for (int j = 0; j < 8; ++j) {
        int id = (int)rintf(samples[j] / dt) - 1;   // jnp.round = RNE
        id = id < 0 ? 0 : (id > NSTEPS - 1 ? NSTEPS - 1 : id);
        id = __builtin_amdgcn_readfirstlane(id);    // wave-uniform -> SGPR
        sidx[j] = id;
        smask |= 1ull << id;
    }
    const float wo0 = w_out[0], wo1 = w_out[1], wo2 = w_out[2];
    const float bo  = b_out[0];

    float yA0 = x[(size_t)rowA * 3 + 0];
    float yA1 = x[(size_t)rowA * 3 + 1];
    float yA2 = x[(size_t)rowA * 3 + 2];
    float yB0 = x[(size_t)rowB * 3 + 0];
    float yB1 = x[(size_t)rowB * 3 + 1];
    float yB2 = x[(size_t)rowB * 3 + 2];

    // ---- prologue: zb = y*W1 + b1 in D-layout, both chains ----
    float4_ zbA0, zbA1, zbB0, zbB1;
    {
        F A1y[2];
#pragma unroll
        for (int H = 0; H < 2; ++H) {
            if (quad == 0) {
                int u = sig(16 * H + col16);
                A1y[H].h2[0] = (half2_){(__fp16)w1[0 * 32 + u], (__fp16)w1[1 * 32 + u]};
                A1y[H].h2[1] = (half2_){(__fp16)w1[2 * 32 + u], (__fp16)b1[u]};
                A1y[H].h2[2] = (half2_)(__fp16)0.0f;
                A1y[H].h2[3] = (half2_)(__fp16)0.0f;
            } else {
#pragma unroll
                for (int pp = 0; pp < 4; ++pp) A1y[H].h2[pp] = (half2_)(__fp16)0.0f;
            }
        }
        float4_ Zc;
#pragma unroll
        for (int r = 0; r < 4; ++r) Zc[r] = 0.0f;
        half2_ aA = __builtin_amdgcn_cvt_pkrtz(yA0, yA1);
        half2_ bA = __builtin_amdgcn_cvt_pkrtz(yA2, 1.0f);
        half2_ aB = __builtin_amdgcn_cvt_pkrtz(yB0, yB1);
        half2_ bB = __builtin_amdgcn_cvt_pkrtz(yB2, 1.0f);
        F ByA, ByB;
        ByA.h2[0] = aA; ByA.h2[1] = bA; ByA.h2[2] = aA; ByA.h2[3] = bA;
        ByB.h2[0] = aB; ByB.h2[1] = bB; ByB.h2[2] = aB; ByB.h2[3] = bB;
        zbA0 = __builtin_amdgcn_mfma_f32_16x16x32_f16(A1y[0].h8, ByA.h8, Zc, 0, 0, 0);
        zbB0 = __builtin_amdgcn_mfma_f32_16x16x32_f16(A1y[0].h8, ByB.h8, Zc, 0, 0, 0);
        zbA1 = __builtin_amdgcn_mfma_f32_16x16x32_f16(A1y[1].h8, ByA.h8, Zc, 0, 0, 0);
        zbB1 = __builtin_amdgcn_mfma_f32_16x16x32_f16(A1y[1].h8, ByB.h8, Zc, 0, 0, 0);
    }

    const half2_ two = (half2_)(__fp16)2.0f;

#pragma unroll 1
    for (int s = 0; s < NSTEPS; ++s) {
        // ================= st0 (A and B interleaved) =================
        F PA, PB;
        PA.h2[0] = relu_pk_f16(zbA0[0], zbA0[1]);
        PB.h2[0] = relu_pk_f16(zbB0[0], zbB0[1]);
        PA.h2[1] = relu_pk_f16(zbA0[2], zbA0[3]);
        PB.h2[1] = relu_pk_f16(zbB0[2], zbB0[3]);
        PA.h2[2] = relu_pk_f16(zbA1[0], zbA1[1]);
        PB.h2[2] = relu_pk_f16(zbB1[0], zbB1[1]);
        PA.h2[3] = relu_pk_f16(zbA1[2], zbA1[3]);
        PB.h2[3] = relu_pk_f16(zbB1[2], zbB1[3]);

        float4_ DA0 = __builtin_amdgcn_mfma_f32_16x16x32_f16(A2[0].h8, PA.h8, Cb[0], 0, 0, 0);
        float4_ DB0 = __builtin_amdgcn_mfma_f32_16x16x32_f16(A2[0].h8, PB.h8, Cb[0], 0, 0, 0);
        float4_ DA1 = __builtin_amdgcn_mfma_f32_16x16x32_f16(A2[1].h8, PA.h8, Cb[1], 0, 0, 0);
        float4_ DB1 = __builtin_amdgcn_mfma_f32_16x16x32_f16(A2[1].h8, PB.h8, Cb[1], 0, 0, 0);

        F QA, QB, SA, SB;
        QA.h2[0] = relu_pk_f16(DA0[0], DA0[1]);
        QB.h2[0] = relu_pk_f16(DB0[0], DB0[1]);
        QA.h2[1] = relu_pk_f16(DA0[2], DA0[3]);
        QB.h2[1] = relu_pk_f16(DB0[2], DB0[3]);
        QA.h2[2] = relu_pk_f16(DA1[0], DA1[1]);
        QB.h2[2] = relu_pk_f16(DB1[0], DB1[1]);
        QA.h2[3] = relu_pk_f16(DA1[2], DA1[3]);
        QB.h2[3] = relu_pk_f16(DB1[2], DB1[3]);
#pragma unroll
        for (int pp = 0; pp < 4; ++pp) { SA.h2[pp] = QA.h2[pp]; SB.h2[pp] = QB.h2[pp]; }

        float4_ zhA0 = zbA0 + cH[0];
        float4_ zhB0 = zbB0 + cH[0];
        float4_ zhA1 = zbA1 + cH[1];
        float4_ zhB1 = zbB1 + cH[1];

        // ================= st1, st2 (ca=2) =================
#pragma unroll
        for (int st = 1; st <= 2; ++st) {
            float4_ GA0 = __builtin_amdgcn_mfma_f32_16x16x32_f16(Mh[0].h8, QA.h8, zhA0, 0, 0, 0);
            float4_ GB0 = __builtin_amdgcn_mfma_f32_16x16x32_f16(Mh[0].h8, QB.h8, zhB0, 0, 0, 0);
            float4_ GA1 = __builtin_amdgcn_mfma_f32_16x16x32_f16(Mh[1].h8, QA.h8, zhA1, 0, 0, 0);
            float4_ GB1 = __builtin_amdgcn_mfma_f32_16x16x32_f16(Mh[1].h8, QB.h8, zhB1, 0, 0, 0);
            PA.h2[0] = relu_pk_f16(GA0[0], GA0[1]);
            PB.h2[0] = relu_pk_f16(GB0[0], GB0[1]);
            PA.h2[1] = relu_pk_f16(GA0[2], GA0[3]);
            PB.h2[1] = relu_pk_f16(GB0[2], GB0[3]);
            PA.h2[2] = relu_pk_f16(GA1[0], GA1[1]);
            PB.h2[2] = relu_pk_f16(GB1[0], GB1[1]);
            PA.h2[3] = relu_pk_f16(GA1[2], GA1[3]);
            PB.h2[3] = relu_pk_f16(GB1[2], GB1[3]);
            float4_ EA0 = __builtin_amdgcn_mfma_f32_16x16x32_f16(A2[0].h8, PA.h8, Cb[0], 0, 0, 0);
            float4_ EB0 = __builtin_amdgcn_mfma_f32_16x16x32_f16(A2[0].h8, PB.h8, Cb[0], 0, 0, 0);
            float4_ EA1 = __builtin_amdgcn_mfma_f32_16x16x32_f16(A2[1].h8, PA.h8, Cb[1], 0, 0, 0);
            float4_ EB1 = __builtin_amdgcn_mfma_f32_16x16x32_f16(A2[1].h8, PB.h8, Cb[1], 0, 0, 0);
            QA.h2[0] = relu_pk_f16(EA0[0], EA0[1]);
            QB.h2[0] = relu_pk_f16(EB0[0], EB0[1]);
            QA.h2[1] = relu_pk_f16(EA0[2], EA0[3]);
            QB.h2[1] = relu_pk_f16(EB0[2], EB0[3]);
            QA.h2[2] = relu_pk_f16(EA1[0], EA1[1]);
            QB.h2[2] = relu_pk_f16(EB1[0], EB1[1]);
            QA.h2[3] = relu_pk_f16(EA1[2], EA1[3]);
            QB.h2[3] = relu_pk_f16(EB1[2], EB1[3]);
#pragma unroll
            for (int pp = 0; pp < 4; ++pp) {
                SA.h2[pp] += two * QA.h2[pp];                    // v_pk_fma_f16
                SB.h2[pp] += two * QB.h2[pp];
            }
        }

        // ================= st3 (ca=1): feed 2*Q into dt2-scaled M ==========
        zhA0 = zhA0 + cH[0];
        zhB0 = zhB0 + cH[0];
        zhA1 = zhA1 + cH[1];
        zhB1 = zhB1 + cH[1];
        F QdA, QdB;
#pragma unroll
        for (int pp = 0; pp < 4; ++pp) {
            QdA.h2[pp] = QA.h2[pp] + QA.h2[pp];                  // exact x2
            QdB.h2[pp] = QB.h2[pp] + QB.h2[pp];
        }
        {
            float4_ GA0 = __builtin_amdgcn_mfma_f32_16x16x32_f16(Mh[0].h8, QdA.h8, zhA0, 0, 0, 0);
            float4_ GB0 = __builtin_amdgcn_mfma_f32_16x16x32_f16(Mh[0].h8, QdB.h8, zhB0, 0, 0, 0);
            float4_ GA1 = __builtin_amdgcn_mfma_f32_16x16x32_f16(Mh[1].h8, QdA.h8, zhA1, 0, 0, 0);
            float4_ GB1 = __builtin_amdgcn_mfma_f32_16x16x32_f16(Mh[1].h8, QdB.h8, zhB1, 0, 0, 0);
            PA.h2[0] = relu_pk_f16(GA0[0], GA0[1]);
            PB.h2[0] = relu_pk_f16(GB0[0], GB0[1]);
            PA.h2[1] = relu_pk_f16(GA0[2], GA0[3]);
            PB.h2[1] = relu_pk_f16(GB0[2], GB0[3]);
            PA.h2[2] = relu_pk_f16(GA1[0], GA1[1]);
            PB.h2[2] = relu_pk_f16(GB1[0], GB1[1]);
            PA.h2[3] = relu_pk_f16(GA1[2], GA1[3]);
            PB.h2[3] = relu_pk_f16(GB1[2], GB1[3]);
            float4_ EA0 = __builtin_amdgcn_mfma_f32_16x16x32_f16(A2[0].h8, PA.h8, Cb[0], 0, 0, 0);
            float4_ EB0 = __builtin_amdgcn_mfma_f32_16x16x32_f16(A2[0].h8, PB.h8, Cb[0], 0, 0, 0);
            float4_ EA1 = __builtin_amdgcn_mfma_f32_16x16x32_f16(A2[1].h8, PA.h8, Cb[1], 0, 0, 0);
            float4_ EB1 = __builtin_amdgcn_mfma_f32_16x16x32_f16(A2[1].h8, PB.h8, Cb[1], 0, 0, 0);
            QA.h2[0] = relu_pk_f16(EA0[0], EA0[1]);
            QB.h2[0] = relu_pk_f16(EB0[0], EB0[1]);
            QA.h2[1] = relu_pk_f16(EA0[2], EA0[3]);
            QB.h2[1] = relu_pk_f16(EB0[2], EB0[3]);
            QA.h2[2] = relu_pk_f16(EA1[0], EA1[1]);
            QB.h2[2] = relu_pk_f16(EB1[0], EB1[1]);
            QA.h2[3] = relu_pk_f16(EA1[2], EA1[3]);
            QB.h2[3] = relu_pk_f16(EB1[2], EB1[3]);
#pragma unroll
            for (int pp = 0; pp < 4; ++pp) {
                SA.h2[pp] += QA.h2[pp];                          // ca=1
                SB.h2[pp] += QB.h2[pp];
            }
        }

        // ================= y-update + z-update =================
        float4_ D3A = __builtin_amdgcn_mfma_f32_16x16x32_f16(A3.h8, SA.h8, C3, 0, 0, 0);
        float4_ D3B = __builtin_amdgcn_mfma_f32_16x16x32_f16(A3.h8, SB.h8, C3, 0, 0, 0);
        zbA0 = __builtin_amdgcn_mfma_f32_16x16x32_f16(Mz[0].h8, SA.h8, zbA0, 0, 0, 0);
        zbB0 = __builtin_amdgcn_mfma_f32_16x16x32_f16(Mz[0].h8, SB.h8, zbB0, 0, 0, 0);
        zbA1 = __builtin_amdgcn_mfma_f32_16x16x32_f16(Mz[1].h8, SA.h8, zbA1, 0, 0, 0);
        zbB1 = __builtin_amdgcn_mfma_f32_16x16x32_f16(Mz[1].h8, SB.h8, zbB1, 0, 0, 0);
#pragma unroll
        for (int r = 0; r < 4; ++r) {
            zbA0[r] = fmaf(2.0f, cH[0][r], zbA0[r]);
            zbB0[r] = fmaf(2.0f, cH[0][r], zbB0[r]);
            zbA1[r] = fmaf(2.0f, cH[1][r], zbA1[r]);
            zbB1[r] = fmaf(2.0f, cH[1][r], zbB1[r]);
        }
        yA0 = fmaf(dt6, D3A[0], yA0);
        yB0 = fmaf(dt6, D3B[0], yB0);
        yA1 = fmaf(dt6, D3A[1], yA1);
        yB1 = fmaf(dt6, D3B[1], yB1);
        yA2 = fmaf(dt6, D3A[2], yA2);
        yB2 = fmaf(dt6, D3B[2], yB2);

        // wave-uniform SALU fast path: most steps store nothing
        if ((smask >> s) & 1ull) {
            if (quad == 0) {
#pragma unroll
                for (int j = 0; j < 8; ++j) {
                    if (sidx[j] == s) {
                        out[(size_t)j * B + rowA] = fmaf(yA2, wo2, fmaf(yA1, wo1, fmaf(yA0, wo0, bo)));
                        out[(size_t)j * B + rowB] = fmaf(yB2, wo2, fmaf(yB1, wo1, fmaf(yB0, wo0, bo)));
                    }
                }
            }
        }
    }
}

extern "C" void kernel_launch(void* const* d_in, const int* in_sizes, int n_in,
                              void* d_out, int out_size, void* d_ws, size_t ws_size,
                              hipStream_t stream) {
    const float* x       = (const float*)d_in[0];
    const float* samples = (const float*)d_in[1];
    const float* w1      = (const float*)d_in[2];
    const float* b1      = (const float*)d_in[3];
    const float* w2      = (const float*)d_in[4];
    const float* b2      = (const float*)d_in[5];
    const float* w3      = (const float*)d_in[6];
    const float* b3      = (const float*)d_in[7];
    const float* w_out   = (const float*)d_in[8];
    const float* b_out   = (const float*)d_in[9];
    float* out = (float*)d_out;

    const int B = in_sizes[0] / 3;           // 131072
    const int rowsPerBlock = 32;             // 1 wave x 2 chains x 16 samples
    const int grid = (B + rowsPerBlock - 1) / rowsPerBlock;   // 4096
    ode_rk4_mfma<<<grid, 64, 0, stream>>>(
        x, samples, w1, b1, w2, b2, w3, b3, w_out, b_out, out, B);
}

// Round 12
// 205.527 us; speedup vs baseline: 1.0423x; 1.0140x over previous
//
#include <hip/hip_runtime.h>

#define NSTEPS 64

typedef __attribute__((ext_vector_type(4)))  float  float4_;   // 16x16 MFMA C/D
typedef __attribute__((ext_vector_type(2)))  __fp16 half2_;    // packed f16
typedef __attribute__((ext_vector_type(8)))  __fp16 half8_;    // f16 MFMA A/B operand

__device__ __forceinline__ half2_ relu_pk_f16(float a, float b) {
    half2_ h = __builtin_amdgcn_cvt_pkrtz(a, b);               // v_cvt_pkrtz_f16_f32
    return __builtin_elementwise_max(h, (half2_)(__fp16)0);    // v_pk_max_f16
}

// R26 (this round): throughput-sum attack + block-size test.
// Evidence: R9(8192 waves) == R11(4096 waves, 2-chain) == 167us => stream
// count is NOT the constraint; wall = VALU+MFMA cycle sum (overlap <= 19us
// in every config). Also R6 (256-thr blocks) beat all 64-thr-block rounds
// despite higher modeled work => suspect per-workgroup dispatch overhead.
// Changes vs R9 (all z-space algebra validated R8/R9):
//  1) 256-thread blocks (4 waves), 2048 blocks.
//  2) y DROPPED from loop: y_T = y0 + dt6*(sum S_n)*W3 + T*dt*b3.
//     SSUM accumulates in packed f16; L3 MFMA only at the 8 sampled steps.
//  3) zb-update C-operand = zh_st3 (= zb+2cH, already live) — kills the
//     trailing zb+=2cH adds.
//  4) Mf = dt-scaled M restored (R8-validated) — kills Qd=2Q adds.
// Per step/wave: 16 MFMA, ~100 VALU (R9: 17 / ~120).
__global__ __launch_bounds__(256, 5)
void ode_rk4_mfma(const float* __restrict__ x,
                  const float* __restrict__ samples,
                  const float* __restrict__ w1, const float* __restrict__ b1,
                  const float* __restrict__ w2, const float* __restrict__ b2,
                  const float* __restrict__ w3, const float* __restrict__ b3,
                  const float* __restrict__ w_out, const float* __restrict__ b_out,
                  float* __restrict__ out, int B)
{
    const int lane  = threadIdx.x & 63;
    const int w     = threadIdx.x >> 6;
    const int col16 = lane & 15;              // this lane's sample (mod 16)
    const int quad  = lane >> 4;              // 0..3 (k-group / row-group)

    const int row = (blockIdx.x * 4 + w) * 16 + col16;

    auto sig = [](int p) -> int {
        int q = (p & 15) >> 2, r = p & 3;
        return q * 8 + r + ((p < 16) ? 0 : 4);
    };

    // ---- scalars ----
    const float maxT = samples[7];
    const float dt   = maxT / 64.0f;
    const float dt2  = 0.5f * dt;
    const float dt6  = dt / 6.0f;

    union F { half2_ h2[4]; half8_ h8; };

    // ---- persistent MFMA operands ----
    // M = W3*W1: Mh (dt2), Mf (dt), Mz (dt6). A[m][k] = ci*M[k][u].
    F Mh[2], Mf[2], Mz[2];
#pragma unroll
    for (int H = 0; H < 2; ++H) {
        int u = sig(16 * H + col16);
#pragma unroll
        for (int pp = 0; pp < 4; ++pp) {
            int kk = quad * 8 + 2 * pp;
            float m0 = w3[kk * 3 + 0] * w1[0 * 32 + u]
                     + w3[kk * 3 + 1] * w1[1 * 32 + u]
                     + w3[kk * 3 + 2] * w1[2 * 32 + u];
            float m1 = w3[(kk + 1) * 3 + 0] * w1[0 * 32 + u]
                     + w3[(kk + 1) * 3 + 1] * w1[1 * 32 + u]
                     + w3[(kk + 1) * 3 + 2] * w1[2 * 32 + u];
            Mh[H].h2[pp] = (half2_){(__fp16)(dt2 * m0), (__fp16)(dt2 * m1)};
            Mf[H].h2[pp] = (half2_){(__fp16)(dt  * m0), (__fp16)(dt  * m1)};
            Mz[H].h2[pp] = (half2_){(__fp16)(dt6 * m0), (__fp16)(dt6 * m1)};
        }
    }

    F A2[2];
    float4_ Cb[2];
#pragma unroll
    for (int H = 0; H < 2; ++H) {
        int u = sig(16 * H + col16);
#pragma unroll
        for (int pp = 0; pp < 4; ++pp) {
            int kk = quad * 8 + 2 * pp;
            A2[H].h2[pp] = (half2_){(__fp16)w2[kk * 32 + u], (__fp16)w2[(kk + 1) * 32 + u]};
        }
#pragma unroll
        for (int r = 0; r < 4; ++r)
            Cb[H][r] = b2[sig(16 * H + quad * 4 + r)];
    }

    // Layer3 A-frag with row duplication (validated): (m&3)<3 carry w3.
    F A3;
    {
        const int  d    = col16 & 3;
        const bool live = d < 3;
#pragma unroll
        for (int pp = 0; pp < 4; ++pp) {
            int kk = quad * 8 + 2 * pp;
            A3.h2[pp] = live
                ? (half2_){(__fp16)w3[kk * 3 + d], (__fp16)w3[(kk + 1) * 3 + d]}
                : (half2_)(__fp16)0.0f;
        }
    }

    // cH = dt2*(b3*W1) in D-layout
    float4_ cH[2];
#pragma unroll
    for (int H = 0; H < 2; ++H)
#pragma unroll
        for (int r = 0; r < 4; ++r) {
            int u = sig(16 * H + quad * 4 + r);
            cH[H][r] = dt2 * (b3[0] * w1[0 * 32 + u] + b3[1] * w1[1 * 32 + u] + b3[2] * w1[2 * 32 + u]);
        }

    int sidx[8];
    unsigned long long smask = 0ull;
#pragma unroll
    for (int j = 0; j < 8; ++j) {
        int id = (int)rintf(samples[j] / dt) - 1;   // jnp.round = RNE
        id = id < 0 ? 0 : (id > NSTEPS - 1 ? NSTEPS - 1 : id);
        id = __builtin_amdgcn_readfirstlane(id);    // wave-uniform -> SGPR
        sidx[j] = id;
        smask |= 1ull << id;
    }
    const float wo0 = w_out[0], wo1 = w_out[1], wo2 = w_out[2];
    const float bo  = b_out[0];
    const float db0 = dt * b3[0], db1 = dt * b3[1], db2 = dt * b3[2];

    const float y00 = x[(size_t)row * 3 + 0];
    const float y01 = x[(size_t)row * 3 + 1];
    const float y02 = x[(size_t)row * 3 + 2];

    // ---- prologue: zb = y*W1 + b1 in D-layout ----
    float4_ zb0, zb1;
    {
        F A1y[2];
#pragma unroll
        for (int H = 0; H < 2; ++H) {
            if (quad == 0) {
                int u = sig(16 * H + col16);
                A1y[H].h2[0] = (half2_){(__fp16)w1[0 * 32 + u], (__fp16)w1[1 * 32 + u]};
                A1y[H].h2[1] = (half2_){(__fp16)w1[2 * 32 + u], (__fp16)b1[u]};
                A1y[H].h2[2] = (half2_)(__fp16)0.0f;
                A1y[H].h2[3] = (half2_)(__fp16)0.0f;
            } else {
#pragma unroll
                for (int pp = 0; pp < 4; ++pp) A1y[H].h2[pp] = (half2_)(__fp16)0.0f;
            }
        }
        float4_ Zc = {0.f, 0.f, 0.f, 0.f};
        half2_ a = __builtin_amdgcn_cvt_pkrtz(y00, y01);
        half2_ b = __builtin_amdgcn_cvt_pkrtz(y02, 1.0f);
        F By;
        By.h2[0] = a; By.h2[1] = b; By.h2[2] = a; By.h2[3] = b;
        zb0 = __builtin_amdgcn_mfma_f32_16x16x32_f16(A1y[0].h8, By.h8, Zc, 0, 0, 0);
        zb1 = __builtin_amdgcn_mfma_f32_16x16x32_f16(A1y[1].h8, By.h8, Zc, 0, 0, 0);
    }

    const half2_ two = (half2_)(__fp16)2.0f;
    F SSUM;
#pragma unroll
    for (int pp = 0; pp < 4; ++pp) SSUM.h2[pp] = (half2_)(__fp16)0.0f;

#pragma unroll 1
    for (int s = 0; s < NSTEPS; ++s) {
        F P, Q, S;

        // ---- st0: P directly from zb; Q0 lands in S (aliased use as st1 B)
        P.h2[0] = relu_pk_f16(zb0[0], zb0[1]);
        P.h2[1] = relu_pk_f16(zb0[2], zb0[3]);
        P.h2[2] = relu_pk_f16(zb1[0], zb1[1]);
        P.h2[3] = relu_pk_f16(zb1[2], zb1[3]);
        float4_ D0 = __builtin_amdgcn_mfma_f32_16x16x32_f16(A2[0].h8, P.h8, Cb[0], 0, 0, 0);
        float4_ D1 = __builtin_amdgcn_mfma_f32_16x16x32_f16(A2[1].h8, P.h8, Cb[1], 0, 0, 0);
        S.h2[0] = relu_pk_f16(D0[0], D0[1]);
        S.h2[1] = relu_pk_f16(D0[2], D0[3]);
        S.h2[2] = relu_pk_f16(D1[0], D1[1]);
        S.h2[3] = relu_pk_f16(D1[2], D1[3]);

        float4_ zh0 = zb0 + cH[0];
        float4_ zh1 = zb1 + cH[1];

        // ---- st1 (B = S == Q0; ca=2) ----
        {
            float4_ G0 = __builtin_amdgcn_mfma_f32_16x16x32_f16(Mh[0].h8, S.h8, zh0, 0, 0, 0);
            float4_ G1 = __builtin_amdgcn_mfma_f32_16x16x32_f16(Mh[1].h8, S.h8, zh1, 0, 0, 0);
            P.h2[0] = relu_pk_f16(G0[0], G0[1]);
            P.h2[1] = relu_pk_f16(G0[2], G0[3]);
            P.h2[2] = relu_pk_f16(G1[0], G1[1]);
            P.h2[3] = relu_pk_f16(G1[2], G1[3]);
            float4_ E0 = __builtin_amdgcn_mfma_f32_16x16x32_f16(A2[0].h8, P.h8, Cb[0], 0, 0, 0);
            float4_ E1 = __builtin_amdgcn_mfma_f32_16x16x32_f16(A2[1].h8, P.h8, Cb[1], 0, 0, 0);
            Q.h2[0] = relu_pk_f16(E0[0], E0[1]);
            Q.h2[1] = relu_pk_f16(E0[2], E0[3]);
            Q.h2[2] = relu_pk_f16(E1[0], E1[1]);
            Q.h2[3] = relu_pk_f16(E1[2], E1[3]);
#pragma unroll
            for (int pp = 0; pp < 4; ++pp) S.h2[pp] += two * Q.h2[pp];
        }

        // ---- st2 (B = Q1; ca=2) ----
        {
            float4_ G0 = __builtin_amdgcn_mfma_f32_16x16x32_f16(Mh[0].h8, Q.h8, zh0, 0, 0, 0);
            float4_ G1 = __builtin_amdgcn_mfma_f32_16x16x32_f16(Mh[1].h8, Q.h8, zh1, 0, 0, 0);
            P.h2[0] = relu_pk_f16(G0[0], G0[1]);
            P.h2[1] = relu_pk_f16(G0[2], G0[3]);
            P.h2[2] = relu_pk_f16(G1[0], G1[1]);
            P.h2[3] = relu_pk_f16(G1[2], G1[3]);
            float4_ E0 = __builtin_amdgcn_mfma_f32_16x16x32_f16(A2[0].h8, P.h8, Cb[0], 0, 0, 0);
            float4_ E1 = __builtin_amdgcn_mfma_f32_16x16x32_f16(A2[1].h8, P.h8, Cb[1], 0, 0, 0);
            Q.h2[0] = relu_pk_f16(E0[0], E0[1]);
            Q.h2[1] = relu_pk_f16(E0[2], E0[3]);
            Q.h2[2] = relu_pk_f16(E1[0], E1[1]);
            Q.h2[3] = relu_pk_f16(E1[2], E1[3]);
#pragma unroll
            for (int pp = 0; pp < 4; ++pp) S.h2[pp] += two * Q.h2[pp];
        }

        // ---- st3 (B = Q2 via dt-scaled Mf; ca=1) ----
        zh0 = zh0 + cH[0];                     // zh = zb + 2*cH
        zh1 = zh1 + cH[1];
        {
            float4_ G0 = __builtin_amdgcn_mfma_f32_16x16x32_f16(Mf[0].h8, Q.h8, zh0, 0, 0, 0);
            float4_ G1 = __builtin_amdgcn_mfma_f32_16x16x32_f16(Mf[1].h8, Q.h8, zh1, 0, 0, 0);
            P.h2[0] = relu_pk_f16(G0[0], G0[1]);
            P.h2[1] = relu_pk_f16(G0[2], G0[3]);
            P.h2[2] = relu_pk_f16(G1[0], G1[1]);
            P.h2[3] = relu_pk_f16(G1[2], G1[3]);
            float4_ E0 = __builtin_amdgcn_mfma_f32_16x16x32_f16(A2[0].h8, P.h8, Cb[0], 0, 0, 0);
            float4_ E1 = __builtin_amdgcn_mfma_f32_16x16x32_f16(A2[1].h8, P.h8, Cb[1], 0, 0, 0);
            Q.h2[0] = relu_pk_f16(E0[0], E0[1]);
            Q.h2[1] = relu_pk_f16(E0[2], E0[3]);
            Q.h2[2] = relu_pk_f16(E1[0], E1[1]);
            Q.h2[3] = relu_pk_f16(E1[2], E1[3]);
#pragma unroll
            for (int pp = 0; pp < 4; ++pp) S.h2[pp] += Q.h2[pp];
        }

        // ---- SSUM accumulate + z-update (C-operand = zh_st3 = zb+2cH) ----
#pragma unroll
        for (int pp = 0; pp < 4; ++pp) SSUM.h2[pp] += S.h2[pp];
        zb0 = __builtin_amdgcn_mfma_f32_16x16x32_f16(Mz[0].h8, S.h8, zh0, 0, 0, 0);
        zb1 = __builtin_amdgcn_mfma_f32_16x16x32_f16(Mz[1].h8, S.h8, zh1, 0, 0, 0);

        // ---- sampled steps only: reconstruct y and store ----
        if ((smask >> s) & 1ull) {
            float4_ Zc = {0.f, 0.f, 0.f, 0.f};
            float4_ D3 = __builtin_amdgcn_mfma_f32_16x16x32_f16(A3.h8, SSUM.h8, Zc, 0, 0, 0);
            float T = (float)(s + 1);
            float o0 = fmaf(dt6, D3[0], fmaf(T, db0, y00));
            float o1 = fmaf(dt6, D3[1], fmaf(T, db1, y01));
            float o2 = fmaf(dt6, D3[2], fmaf(T, db2, y02));
            if (quad == 0) {
#pragma unroll
                for (int j = 0; j < 8; ++j) {
                    if (sidx[j] == s) {
                        out[(size_t)j * B + row] = fmaf(o2, wo2, fmaf(o1, wo1, fmaf(o0, wo0, bo)));
                    }
                }
            }
        }
    }
}

extern "C" void kernel_launch(void* const* d_in, const int* in_sizes, int n_in,
                              void* d_out, int out_size, void* d_ws, size_t ws_size,
                              hipStream_t stream) {
    const float* x       = (const float*)d_in[0];
    const float* samples = (const float*)d_in[1];
    const float* w1      = (const float*)d_in[2];
    const float* b1      = (const float*)d_in[3];
    const float* w2      = (const float*)d_in[4];
    const float* b2      = (const float*)d_in[5];
    const float* w3      = (const float*)d_in[6];
    const float* b3      = (const float*)d_in[7];
    const float* w_out   = (const float*)d_in[8];
    const float* b_out   = (const float*)d_in[9];
    float* out = (float*)d_out;

    const int B = in_sizes[0] / 3;           // 131072
    const int rowsPerBlock = 64;             // 4 waves x 16 samples
    const int grid = (B + rowsPerBlock - 1) / rowsPerBlock;   // 2048
    ode_rk4_mfma<<<grid, 256, 0, stream>>>(
        x, samples, w1, b1, w2, b2, w3, b3, w_out, b_out, out, B);
}

// Round 13
// 202.737 us; speedup vs baseline: 1.0566x; 1.0138x over previous
//
#include <hip/hip_runtime.h>

#define NSTEPS 64

typedef __attribute__((ext_vector_type(4)))  float  float4_;   // 16x16 MFMA C/D
typedef __attribute__((ext_vector_type(2)))  __fp16 half2_;    // packed f16
typedef __attribute__((ext_vector_type(8)))  __fp16 half8_;    // f16 MFMA A/B operand

__device__ __forceinline__ half2_ relu_pk_f16(float a, float b) {
    half2_ h = __builtin_amdgcn_cvt_pkrtz(a, b);               // v_cvt_pkrtz_f16_f32
    return __builtin_elementwise_max(h, (half2_)(__fp16)0);    // v_pk_max_f16
}

// R27 (this round): R12 with the spill fixed — ONE change.
// R12 evidence: WRITE_SIZE 4096->16300 KB, FETCH 830->5630 KB = scratch
// spill; (256,5) cap 102 unified regs < ~110 demand. Despite paying ~12MB
// of spill traffic, R12 hit 161us (best of 16-shape line) => the schedule
// (16 MFMA/step, y-out-of-loop, zh-reuse) is good; the experiment was
// contaminated. (256,4) caps 128 — fits spill-free; occupancy drops 5->4
// waves/SIMD which R2-R11 showed is not binding (wall invariant 19-48%).
// Numerics identical to R12 (passed, absmax 0.0039):
//   zb = y*W1+b1 recurrence; Mh(dt2)/Mf(dt)/Mz(dt6); S = Q0+2Q1+2Q2+Q3;
//   zb' = Mz^T S + (zb+2cH); y_T = y0 + dt6*(SSUM*W3) + T*dt*b3 at the 8
//   sampled steps only.
__global__ __launch_bounds__(256, 4)
void ode_rk4_mfma(const float* __restrict__ x,
                  const float* __restrict__ samples,
                  const float* __restrict__ w1, const float* __restrict__ b1,
                  const float* __restrict__ w2, const float* __restrict__ b2,
                  const float* __restrict__ w3, const float* __restrict__ b3,
                  const float* __restrict__ w_out, const float* __restrict__ b_out,
                  float* __restrict__ out, int B)
{
    const int lane  = threadIdx.x & 63;
    const int w     = threadIdx.x >> 6;
    const int col16 = lane & 15;              // this lane's sample (mod 16)
    const int quad  = lane >> 4;              // 0..3 (k-group / row-group)

    const int row = (blockIdx.x * 4 + w) * 16 + col16;

    auto sig = [](int p) -> int {
        int q = (p & 15) >> 2, r = p & 3;
        return q * 8 + r + ((p < 16) ? 0 : 4);
    };

    // ---- scalars ----
    const float maxT = samples[7];
    const float dt   = maxT / 64.0f;
    const float dt2  = 0.5f * dt;
    const float dt6  = dt / 6.0f;

    union F { half2_ h2[4]; half8_ h8; };

    // ---- persistent MFMA operands ----
    // M = W3*W1: Mh (dt2), Mf (dt), Mz (dt6). A[m][k] = ci*M[k][u].
    F Mh[2], Mf[2], Mz[2];
#pragma unroll
    for (int H = 0; H < 2; ++H) {
        int u = sig(16 * H + col16);
#pragma unroll
        for (int pp = 0; pp < 4; ++pp) {
            int kk = quad * 8 + 2 * pp;
            float m0 = w3[kk * 3 + 0] * w1[0 * 32 + u]
                     + w3[kk * 3 + 1] * w1[1 * 32 + u]
                     + w3[kk * 3 + 2] * w1[2 * 32 + u];
            float m1 = w3[(kk + 1) * 3 + 0] * w1[0 * 32 + u]
                     + w3[(kk + 1) * 3 + 1] * w1[1 * 32 + u]
                     + w3[(kk + 1) * 3 + 2] * w1[2 * 32 + u];
            Mh[H].h2[pp] = (half2_){(__fp16)(dt2 * m0), (__fp16)(dt2 * m1)};
            Mf[H].h2[pp] = (half2_){(__fp16)(dt  * m0), (__fp16)(dt  * m1)};
            Mz[H].h2[pp] = (half2_){(__fp16)(dt6 * m0), (__fp16)(dt6 * m1)};
        }
    }

    F A2[2];
    float4_ Cb[2];
#pragma unroll
    for (int H = 0; H < 2; ++H) {
        int u = sig(16 * H + col16);
#pragma unroll
        for (int pp = 0; pp < 4; ++pp) {
            int kk = quad * 8 + 2 * pp;
            A2[H].h2[pp] = (half2_){(__fp16)w2[kk * 32 + u], (__fp16)w2[(kk + 1) * 32 + u]};
        }
#pragma unroll
        for (int r = 0; r < 4; ++r)
            Cb[H][r] = b2[sig(16 * H + quad * 4 + r)];
    }

    // Layer3 A-frag with row duplication (validated): (m&3)<3 carry w3.
    F A3;
    {
        const int  d    = col16 & 3;
        const bool live = d < 3;
#pragma unroll
        for (int pp = 0; pp < 4; ++pp) {
            int kk = quad * 8 + 2 * pp;
            A3.h2[pp] = live
                ? (half2_){(__fp16)w3[kk * 3 + d], (__fp16)w3[(kk + 1) * 3 + d]}
                : (half2_)(__fp16)0.0f;
        }
    }

    // cH = dt2*(b3*W1) in D-layout
    float4_ cH[2];
#pragma unroll
    for (int H = 0; H < 2; ++H)
#pragma unroll
        for (int r = 0; r < 4; ++r) {
            int u = sig(16 * H + quad * 4 + r);
            cH[H][r] = dt2 * (b3[0] * w1[0 * 32 + u] + b3[1] * w1[1 * 32 + u] + b3[2] * w1[2 * 32 + u]);
        }

    int sidx[8];
    unsigned long long smask = 0ull;
#pragma unroll
    for (int j = 0; j < 8; ++j) {
        int id = (int)rintf(samples[j] / dt) - 1;   // jnp.round = RNE
        id = id < 0 ? 0 : (id > NSTEPS - 1 ? NSTEPS - 1 : id);
        id = __builtin_amdgcn_readfirstlane(id);    // wave-uniform -> SGPR
        sidx[j] = id;
        smask |= 1ull << id;
    }
    const float wo0 = w_out[0], wo1 = w_out[1], wo2 = w_out[2];
    const float bo  = b_out[0];
    const float db0 = dt * b3[0], db1 = dt * b3[1], db2 = dt * b3[2];

    const float y00 = x[(size_t)row * 3 + 0];
    const float y01 = x[(size_t)row * 3 + 1];
    const float y02 = x[(size_t)row * 3 + 2];

    // ---- prologue: zb = y*W1 + b1 in D-layout ----
    float4_ zb0, zb1;
    {
        F A1y[2];
#pragma unroll
        for (int H = 0; H < 2; ++H) {
            if (quad == 0) {
                int u = sig(16 * H + col16);
                A1y[H].h2[0] = (half2_){(__fp16)w1[0 * 32 + u], (__fp16)w1[1 * 32 + u]};
                A1y[H].h2[1] = (half2_){(__fp16)w1[2 * 32 + u], (__fp16)b1[u]};
                A1y[H].h2[2] = (half2_)(__fp16)0.0f;
                A1y[H].h2[3] = (half2_)(__fp16)0.0f;
            } else {
#pragma unroll
                for (int pp = 0; pp < 4; ++pp) A1y[H].h2[pp] = (half2_)(__fp16)0.0f;
            }
        }
        float4_ Zc = {0.f, 0.f, 0.f, 0.f};
        half2_ a = __builtin_amdgcn_cvt_pkrtz(y00, y01);
        half2_ b = __builtin_amdgcn_cvt_pkrtz(y02, 1.0f);
        F By;
        By.h2[0] = a; By.h2[1] = b; By.h2[2] = a; By.h2[3] = b;
        zb0 = __builtin_amdgcn_mfma_f32_16x16x32_f16(A1y[0].h8, By.h8, Zc, 0, 0, 0);
        zb1 = __builtin_amdgcn_mfma_f32_16x16x32_f16(A1y[1].h8, By.h8, Zc, 0, 0, 0);
    }

    const half2_ two = (half2_)(__fp16)2.0f;
    F SSUM;
#pragma unroll
    for (int pp = 0; pp < 4; ++pp) SSUM.h2[pp] = (half2_)(__fp16)0.0f;

#pragma unroll 1
    for (int s = 0; s < NSTEPS; ++s) {
        F P, Q, S;

        // ---- st0: P directly from zb; Q0 lands in S (aliased use as st1 B)
        P.h2[0] = relu_pk_f16(zb0[0], zb0[1]);
        P.h2[1] = relu_pk_f16(zb0[2], zb0[3]);
        P.h2[2] = relu_pk_f16(zb1[0], zb1[1]);
        P.h2[3] = relu_pk_f16(zb1[2], zb1[3]);
        float4_ D0 = __builtin_amdgcn_mfma_f32_16x16x32_f16(A2[0].h8, P.h8, Cb[0], 0, 0, 0);
        float4_ D1 = __builtin_amdgcn_mfma_f32_16x16x32_f16(A2[1].h8, P.h8, Cb[1], 0, 0, 0);
        S.h2[0] = relu_pk_f16(D0[0], D0[1]);
        S.h2[1] = relu_pk_f16(D0[2], D0[3]);
        S.h2[2] = relu_pk_f16(D1[0], D1[1]);
        S.h2[3] = relu_pk_f16(D1[2], D1[3]);

        float4_ zh0 = zb0 + cH[0];
        float4_ zh1 = zb1 + cH[1];

        // ---- st1 (B = S == Q0; ca=2) ----
        {
            float4_ G0 = __builtin_amdgcn_mfma_f32_16x16x32_f16(Mh[0].h8, S.h8, zh0, 0, 0, 0);
            float4_ G1 = __builtin_amdgcn_mfma_f32_16x16x32_f16(Mh[1].h8, S.h8, zh1, 0, 0, 0);
            P.h2[0] = relu_pk_f16(G0[0], G0[1]);
            P.h2[1] = relu_pk_f16(G0[2], G0[3]);
            P.h2[2] = relu_pk_f16(G1[0], G1[1]);
            P.h2[3] = relu_pk_f16(G1[2], G1[3]);
            float4_ E0 = __builtin_amdgcn_mfma_f32_16x16x32_f16(A2[0].h8, P.h8, Cb[0], 0, 0, 0);
            float4_ E1 = __builtin_amdgcn_mfma_f32_16x16x32_f16(A2[1].h8, P.h8, Cb[1], 0, 0, 0);
            Q.h2[0] = relu_pk_f16(E0[0], E0[1]);
            Q.h2[1] = relu_pk_f16(E0[2], E0[3]);
            Q.h2[2] = relu_pk_f16(E1[0], E1[1]);
            Q.h2[3] = relu_pk_f16(E1[2], E1[3]);
#pragma unroll
            for (int pp = 0; pp < 4; ++pp) S.h2[pp] += two * Q.h2[pp];
        }

        // ---- st2 (B = Q1; ca=2) ----
        {
            float4_ G0 = __builtin_amdgcn_mfma_f32_16x16x32_f16(Mh[0].h8, Q.h8, zh0, 0, 0, 0);
            float4_ G1 = __builtin_amdgcn_mfma_f32_16x16x32_f16(Mh[1].h8, Q.h8, zh1, 0, 0, 0);
            P.h2[0] = relu_pk_f16(G0[0], G0[1]);
            P.h2[1] = relu_pk_f16(G0[2], G0[3]);
            P.h2[2] = relu_pk_f16(G1[0], G1[1]);
            P.h2[3] = relu_pk_f16(G1[2], G1[3]);
            float4_ E0 = __builtin_amdgcn_mfma_f32_16x16x32_f16(A2[0].h8, P.h8, Cb[0], 0, 0, 0);
            float4_ E1 = __builtin_amdgcn_mfma_f32_16x16x32_f16(A2[1].h8, P.h8, Cb[1], 0, 0, 0);
            Q.h2[0] = relu_pk_f16(E0[0], E0[1]);
            Q.h2[1] = relu_pk_f16(E0[2], E0[3]);
            Q.h2[2] = relu_pk_f16(E1[0], E1[1]);
            Q.h2[3] = relu_pk_f16(E1[2], E1[3]);
#pragma unroll
            for (int pp = 0; pp < 4; ++pp) S.h2[pp] += two * Q.h2[pp];
        }

        // ---- st3 (B = Q2 via dt-scaled Mf; ca=1) ----
        zh0 = zh0 + cH[0];                     // zh = zb + 2*cH
        zh1 = zh1 + cH[1];
        {
            float4_ G0 = __builtin_amdgcn_mfma_f32_16x16x32_f16(Mf[0].h8, Q.h8, zh0, 0, 0, 0);
            float4_ G1 = __builtin_amdgcn_mfma_f32_16x16x32_f16(Mf[1].h8, Q.h8, zh1, 0, 0, 0);
            P.h2[0] = relu_pk_f16(G0[0], G0[1]);
            P.h2[1] = relu_pk_f16(G0[2], G0[3]);
            P.h2[2] = relu_pk_f16(G1[0], G1[1]);
            P.h2[3] = relu_pk_f16(G1[2], G1[3]);
            float4_ E0 = __builtin_amdgcn_mfma_f32_16x16x32_f16(A2[0].h8, P.h8, Cb[0], 0, 0, 0);
            float4_ E1 = __builtin_amdgcn_mfma_f32_16x16x32_f16(A2[1].h8, P.h8, Cb[1], 0, 0, 0);
            Q.h2[0] = relu_pk_f16(E0[0], E0[1]);
            Q.h2[1] = relu_pk_f16(E0[2], E0[3]);
            Q.h2[2] = relu_pk_f16(E1[0], E1[1]);
            Q.h2[3] = relu_pk_f16(E1[2], E1[3]);
#pragma unroll
            for (int pp = 0; pp < 4; ++pp) S.h2[pp] += Q.h2[pp];
        }

        // ---- SSUM accumulate + z-update (C-operand = zh_st3 = zb+2cH) ----
#pragma unroll
        for (int pp = 0; pp < 4; ++pp) SSUM.h2[pp] += S.h2[pp];
        zb0 = __builtin_amdgcn_mfma_f32_16x16x32_f16(Mz[0].h8, S.h8, zh0, 0, 0, 0);
        zb1 = __builtin_amdgcn_mfma_f32_16x16x32_f16(Mz[1].h8, S.h8, zh1, 0, 0, 0);

        // ---- sampled steps only: reconstruct y and store ----
        if ((smask >> s) & 1ull) {
            float4_ Zc = {0.f, 0.f, 0.f, 0.f};
            float4_ D3 = __builtin_amdgcn_mfma_f32_16x16x32_f16(A3.h8, SSUM.h8, Zc, 0, 0, 0);
            float T = (float)(s + 1);
            float o0 = fmaf(dt6, D3[0], fmaf(T, db0, y00));
            float o1 = fmaf(dt6, D3[1], fmaf(T, db1, y01));
            float o2 = fmaf(dt6, D3[2], fmaf(T, db2, y02));
            if (quad == 0) {
#pragma unroll
                for (int j = 0; j < 8; ++j) {
                    if (sidx[j] == s) {
                        out[(size_t)j * B + row] = fmaf(o2, wo2, fmaf(o1, wo1, fmaf(o0, wo0, bo)));
                    }
                }
            }
        }
    }
}

extern "C" void kernel_launch(void* const* d_in, const int* in_sizes, int n_in,
                              void* d_out, int out_size, void* d_ws, size_t ws_size,
                              hipStream_t stream) {
    const float* x       = (const float*)d_in[0];
    const float* samples = (const float*)d_in[1];
    const float* w1      = (const float*)d_in[2];
    const float* b1      = (const float*)d_in[3];
    const float* w2      = (const float*)d_in[4];
    const float* b2      = (const float*)d_in[5];
    const float* w3      = (const float*)d_in[6];
    const float* b3      = (const float*)d_in[7];
    const float* w_out   = (const float*)d_in[8];
    const float* b_out   = (const float*)d_in[9];
    float* out = (float*)d_out;

    const int B = in_sizes[0] / 3;           // 131072
    const int rowsPerBlock = 64;             // 4 waves x 16 samples
    const int grid = (B + rowsPerBlock - 1) / rowsPerBlock;   // 2048
    ode_rk4_mfma<<<grid, 256, 0, stream>>>(
        x, samples, w1, b1, w2, b2, w3, b3, w_out, b_out, out, B);
}